// Round 4
// baseline (812.182 us; speedup 1.0000x reference)
//
#include <hip/hip_runtime.h>

#define C_DIM 256
#define STEPS 20
#define ROWS_PER_WG 32

typedef _Float16 f16;
typedef f16 f16x4 __attribute__((ext_vector_type(4)));
typedef f16 f16x8 __attribute__((ext_vector_type(8)));
typedef float f32x4 __attribute__((ext_vector_type(4)));

// ---------------------------------------------------------------------------
// prep: W'[k][n] = 0.5*W[k][n] + 0.5*K[(k-n+2) mod 256 if <5]
// stored as A-fragments of the TRANSPOSED gemm (A = W'^T):
//   frag f = mt*8+kb : lane l holds A[n = mt*16+(l&15)][k = kb*32+(l>>4)*8+j]
//                      = W'[k][n],  j = 0..7
//   hi = f16(v) ; lo = f16((v-hi)*4096)
// ---------------------------------------------------------------------------
__global__ __launch_bounds__(256) void prep_w(const float* __restrict__ W,
                                              const float* __restrict__ Kl,
                                              f16* __restrict__ whi,
                                              f16* __restrict__ wlo)
{
    const int f = (int)(blockIdx.x * blockDim.x + threadIdx.x) >> 6;  // 0..127
    const int l = (int)threadIdx.x & 63;
    if (f >= 128) return;
    const int mt = f >> 3, kb = f & 7;
    const int n = mt * 16 + (l & 15);
    const int kbase = kb * 32 + (l >> 4) * 8;
    f16 h[8], lo[8];
    #pragma unroll
    for (int j = 0; j < 8; ++j) {
        const int k = kbase + j;
        float v = 0.5f * W[k * C_DIM + n];
        const int d = (k - n + 2) & (C_DIM - 1);
        if (d < 5) v += 0.5f * Kl[d];
        const f16 hh = (f16)v;
        h[j] = hh;
        lo[j] = (f16)((v - (float)hh) * 4096.0f);
    }
    const size_t off = (size_t)f * 512 + (size_t)l * 8;
    *(f16x8*)(whi + off) = *(f16x8*)h;
    *(f16x8*)(wlo + off) = *(f16x8*)lo;
}

// ---------------------------------------------------------------------------
// main: 512 thr = 8 waves. Transposed GEMM D[n][m] = W'^T x mapped^T.
// Wave w owns channel tiles mt = {2w, 2w+1} (A = W' fragments in 128 VGPRs),
// all 32 batch rows (nt = 0,1). Per step: 32 ds_read_b128 + 96 MFMA + 8
// ds_write_b64 per wave; ONE barrier.
//
// LDS planes: [m=0..31][256 ch as f16], row = 512 B = 32 chunks of 16 B,
// channel-chunk c stored at physical chunk p = c ^ ((m&7)<<2).
//   read  (kb,kg): c = kb*4+kg  -> 64 lanes span all 32 chunks, 2 rows each (free)
//   write (mti,kg): 8 B halves  -> 16 chunks x 2 halves x 2 rows (2-way, free)
// hi plane +0, lo plane +16384, double buffer +32768 ; total 64 KiB.
// C-fragment: lane l, tile (mti,nt), reg r <-> ch n=(2w+mti)*16+kg*4+r,
// batch m = nt*16+cl  (4 CONSECUTIVE channels per lane -> b64 writes).
// ---------------------------------------------------------------------------
__global__ __launch_bounds__(512, 2) void cml_main(
    const float* __restrict__ drive,
    const float* __restrict__ r_,
    const float* __restrict__ eps_,
    const float* __restrict__ beta_,
    const f16* __restrict__ whi,
    const f16* __restrict__ wlo,
    float* __restrict__ out)
{
    __shared__ char smem[65536];

    const int tid = (int)threadIdx.x;
    const int w   = tid >> 6;            // wave 0..7
    const int l   = tid & 63;
    const int kg  = l >> 4;              // 0..3
    const int cl  = l & 15;
    const size_t rowBase = (size_t)blockIdx.x * ROWS_PER_WG;

    // ---- one-time: W' A-fragments into registers (32 frags = 128 VGPRs) ----
    f16x8 Wh[2][8], Wl[2][8];
    #pragma unroll
    for (int mti = 0; mti < 2; ++mti) {
        #pragma unroll
        for (int kb = 0; kb < 8; ++kb) {
            const size_t off = (size_t)((w * 2 + mti) * 8 + kb) * 512 + (size_t)l * 8;
            Wh[mti][kb] = *(const f16x8*)(whi + off);
            Wl[mti][kb] = *(const f16x8*)(wlo + off);
        }
    }

    // ---- one-time: per-channel params (ch = (2w+mti)*16 + kg*4 + r) ----
    float rr[2][4], P1[2][4], P2[2][4];
    #pragma unroll
    for (int mti = 0; mti < 2; ++mti) {
        const int ch0 = (w * 2 + mti) * 16 + kg * 4;
        #pragma unroll
        for (int r = 0; r < 4; ++r) {
            const int ch = ch0 + r;
            const float rv = r_[ch], ev = eps_[ch], bv = beta_[ch];
            rr[mti][r] = rv;
            P1[mti][r] = (1.0f - bv) * (1.0f - ev);
            P2[mti][r] = (1.0f - bv) * ev;
        }
    }

    // ---- one-time: drive -> g, beta*drive -> drv ----
    float g[2][2][4], m_[2][2][4], drv[2][2][4];
    #pragma unroll
    for (int mti = 0; mti < 2; ++mti) {
        const int ch0 = (w * 2 + mti) * 16 + kg * 4;
        #pragma unroll
        for (int nt = 0; nt < 2; ++nt) {
            const size_t row = rowBase + (size_t)(nt * 16 + cl);
            const f32x4 d4 = *(const f32x4*)(drive + row * C_DIM + ch0);
            #pragma unroll
            for (int r = 0; r < 4; ++r) {
                const float bv = beta_[ch0 + r];
                g[mti][nt][r]   = d4[r];
                drv[mti][nt][r] = bv * d4[r];
            }
        }
    }

    // ---- precompute LDS addresses ----
    int rbase[2], woff[2][2];
    #pragma unroll
    for (int nt = 0; nt < 2; ++nt) {
        const int m = nt * 16 + cl;
        rbase[nt] = (m << 9) + (kg << 4) + ((m & 7) << 6);
        #pragma unroll
        for (int mti = 0; mti < 2; ++mti) {
            const int c = (w * 2 + mti) * 2 + (kg >> 1);
            const int p = c ^ ((m & 7) << 2);
            woff[mti][nt] = (m << 9) + (p << 4) + ((kg & 1) << 3);
        }
    }

    // ---- prologue: E for step 0 into buf0 ----
    #pragma unroll
    for (int mti = 0; mti < 2; ++mti) {
        #pragma unroll
        for (int nt = 0; nt < 2; ++nt) {
            f16x4 hv, lv;
            #pragma unroll
            for (int r = 0; r < 4; ++r) {
                const float gv = g[mti][nt][r];
                const float mv = rr[mti][r] * gv * (1.0f - gv);
                m_[mti][nt][r] = mv;
                const f16 hh = (f16)mv;
                hv[r] = hh;
                lv[r] = (f16)((mv - (float)hh) * 4096.0f);
            }
            *(f16x4*)(smem + woff[mti][nt]) = hv;
            *(f16x4*)(smem + woff[mti][nt] + 16384) = lv;
        }
    }

    #pragma unroll 1
    for (int s = 0; s < STEPS; ++s) {
        __syncthreads();                       // planes for step s complete
        const int rb = (s & 1) << 15;          // current buffer
        const int wb = rb ^ 32768;             // next buffer

        #pragma unroll
        for (int nt = 0; nt < 2; ++nt) {
            f32x4 acch[2], accl[2];
            #pragma unroll
            for (int mti = 0; mti < 2; ++mti) {
                acch[mti] = (f32x4)0.0f;
                accl[mti] = (f32x4)0.0f;
            }

            const int Ab = rbase[nt] | rb;
            #pragma unroll
            for (int kb = 0; kb < 8; ++kb) {
                const int addr = Ab ^ (kb << 6);
                const f16x8 bh = *(const f16x8*)(smem + addr);
                const f16x8 bl = *(const f16x8*)(smem + addr + 16384);
                #pragma unroll
                for (int mti = 0; mti < 2; ++mti) {
                    acch[mti] = __builtin_amdgcn_mfma_f32_16x16x32_f16(Wh[mti][kb], bh, acch[mti], 0, 0, 0);
                    accl[mti] = __builtin_amdgcn_mfma_f32_16x16x32_f16(Wl[mti][kb], bh, accl[mti], 0, 0, 0);
                    accl[mti] = __builtin_amdgcn_mfma_f32_16x16x32_f16(Wh[mti][kb], bl, accl[mti], 0, 0, 0);
                }
            }

            // physics + next-step map/split/write for this nt half
            #pragma unroll
            for (int mti = 0; mti < 2; ++mti) {
                f16x4 hv, lv;
                #pragma unroll
                for (int r = 0; r < 4; ++r) {
                    const float coupled = fmaf(accl[mti][r], 1.0f / 4096.0f, acch[mti][r]);
                    const float gn = fmaf(P1[mti][r], m_[mti][nt][r],
                                     fmaf(P2[mti][r], coupled, drv[mti][nt][r]));
                    g[mti][nt][r] = gn;
                    const float mv = rr[mti][r] * gn * (1.0f - gn);
                    m_[mti][nt][r] = mv;
                    const f16 hh = (f16)mv;
                    hv[r] = hh;
                    lv[r] = (f16)((mv - (float)hh) * 4096.0f);
                }
                if (s != STEPS - 1) {
                    *(f16x4*)(smem + (woff[mti][nt] | wb)) = hv;
                    *(f16x4*)(smem + (woff[mti][nt] | wb) + 16384) = lv;
                }
            }
        }
    }

    // ---- epilogue: clip + store ----
    #pragma unroll
    for (int mti = 0; mti < 2; ++mti) {
        const int ch0 = (w * 2 + mti) * 16 + kg * 4;
        #pragma unroll
        for (int nt = 0; nt < 2; ++nt) {
            const size_t row = rowBase + (size_t)(nt * 16 + cl);
            f32x4 o;
            #pragma unroll
            for (int r = 0; r < 4; ++r) {
                o[r] = fminf(fmaxf(g[mti][nt][r], 1e-4f), 1.0f - 1e-4f);
            }
            *(f32x4*)(out + row * C_DIM + ch0) = o;
        }
    }
}

extern "C" void kernel_launch(void* const* d_in, const int* in_sizes, int n_in,
                              void* d_out, int out_size, void* d_ws, size_t ws_size,
                              hipStream_t stream) {
    (void)n_in; (void)ws_size; (void)out_size;
    const float* drive = (const float*)d_in[0];
    const float* r     = (const float*)d_in[1];
    const float* eps   = (const float*)d_in[2];
    const float* beta  = (const float*)d_in[3];
    const float* Kl    = (const float*)d_in[4];
    const float* W     = (const float*)d_in[5];
    float* out = (float*)d_out;

    f16* whi = (f16*)d_ws;            // 128 KiB
    f16* wlo = whi + 65536;           // 128 KiB

    prep_w<<<dim3(32), dim3(256), 0, stream>>>(W, Kl, whi, wlo);

    const int nrows = in_sizes[0] / C_DIM;        // 131072
    cml_main<<<dim3((unsigned)(nrows / ROWS_PER_WG)), dim3(512), 0, stream>>>(
        drive, r, eps, beta, whi, wlo, out);
}

// Round 5
// 721.084 us; speedup vs baseline: 1.1263x; 1.1263x over previous
//
#include <hip/hip_runtime.h>

#define C_DIM 256
#define STEPS 20
#define ROWS_PER_WG 32

typedef _Float16 f16;
typedef f16 f16x4 __attribute__((ext_vector_type(4)));
typedef f16 f16x8 __attribute__((ext_vector_type(8)));
typedef float f32x4 __attribute__((ext_vector_type(4)));

// ---------------------------------------------------------------------------
// prep: W'[k][n] = 0.5*W[k][n] + 0.5*K[(k-n+2) mod 256 if <5]
// stored as A-fragments of the TRANSPOSED gemm (A = W'^T):
//   frag f = mt*8+kb : lane l holds A[n = mt*16+(l&15)][k = kb*32+(l>>4)*8+j]
//                      = W'[k][n],  j = 0..7
//   hi = f16(v) ; lo = f16((v-hi)*4096)
// ---------------------------------------------------------------------------
__global__ __launch_bounds__(256) void prep_w(const float* __restrict__ W,
                                              const float* __restrict__ Kl,
                                              f16* __restrict__ whi,
                                              f16* __restrict__ wlo)
{
    const int f = (int)(blockIdx.x * blockDim.x + threadIdx.x) >> 6;  // 0..127
    const int l = (int)threadIdx.x & 63;
    if (f >= 128) return;
    const int mt = f >> 3, kb = f & 7;
    const int n = mt * 16 + (l & 15);
    const int kbase = kb * 32 + (l >> 4) * 8;
    f16 h[8], lo[8];
    #pragma unroll
    for (int j = 0; j < 8; ++j) {
        const int k = kbase + j;
        float v = 0.5f * W[k * C_DIM + n];
        const int d = (k - n + 2) & (C_DIM - 1);
        if (d < 5) v += 0.5f * Kl[d];
        const f16 hh = (f16)v;
        h[j] = hh;
        lo[j] = (f16)((v - (float)hh) * 4096.0f);
    }
    const size_t off = (size_t)f * 512 + (size_t)l * 8;
    *(f16x8*)(whi + off) = *(f16x8*)h;
    *(f16x8*)(wlo + off) = *(f16x8*)lo;
}

// ---------------------------------------------------------------------------
// main: 512 thr = 8 waves. Transposed GEMM D[n][m] = W'^T x mapped^T.
// Wave w owns channel tiles mt = {2w, 2w+1} (A = W' fragments in 128 VGPRs),
// all 32 batch rows (nt = 0,1). Per step: 32 ds_read_b128 + 96 MFMA + 8
// ds_write_b64 per wave; ONE barrier.
//
// LDS planes: [m=0..31][256 ch as f16], row = 512 B = 32 chunks of 16 B.
// Channel-chunk c stored at physical chunk p = c ^ (m & 7).
// Bank-group of a 16B chunk is p mod 8 (32 banks / 4 banks per chunk):
//   read  (nt,kb): 8-lane phase (kg fixed, cl 0..7): p&7 = ((kb&1)<<2)^kg^cl
//                  -> bijection over cl -> conflict-free.         [R4 bug: was <<2]
//   write (mti,nt): p&7 = (c_w&7)^cl -> bijection -> conflict-free (b64 = 2 banks).
// hi plane +0, lo plane +16384, double buffer +32768 ; total 64 KiB.
// C-fragment: lane l, tile (mti,nt), reg r <-> ch n=(2w+mti)*16+kg*4+r,
// batch m = nt*16+cl  (4 CONSECUTIVE channels per lane -> b64 writes).
// ---------------------------------------------------------------------------
__global__ __launch_bounds__(512, 2) void cml_main(
    const float* __restrict__ drive,
    const float* __restrict__ r_,
    const float* __restrict__ eps_,
    const float* __restrict__ beta_,
    const f16* __restrict__ whi,
    const f16* __restrict__ wlo,
    float* __restrict__ out)
{
    __shared__ char smem[65536];

    const int tid = (int)threadIdx.x;
    const int w   = tid >> 6;            // wave 0..7
    const int l   = tid & 63;
    const int kg  = l >> 4;              // 0..3
    const int cl  = l & 15;
    const size_t rowBase = (size_t)blockIdx.x * ROWS_PER_WG;

    // ---- one-time: W' A-fragments into registers (32 frags = 128 VGPRs) ----
    f16x8 Wh[2][8], Wl[2][8];
    #pragma unroll
    for (int mti = 0; mti < 2; ++mti) {
        #pragma unroll
        for (int kb = 0; kb < 8; ++kb) {
            const size_t off = (size_t)((w * 2 + mti) * 8 + kb) * 512 + (size_t)l * 8;
            Wh[mti][kb] = *(const f16x8*)(whi + off);
            Wl[mti][kb] = *(const f16x8*)(wlo + off);
        }
    }

    // ---- one-time: per-channel params (ch = (2w+mti)*16 + kg*4 + r) ----
    float rr[2][4], P1[2][4], P2[2][4];
    #pragma unroll
    for (int mti = 0; mti < 2; ++mti) {
        const int ch0 = (w * 2 + mti) * 16 + kg * 4;
        #pragma unroll
        for (int r = 0; r < 4; ++r) {
            const int ch = ch0 + r;
            const float rv = r_[ch], ev = eps_[ch], bv = beta_[ch];
            rr[mti][r] = rv;
            P1[mti][r] = (1.0f - bv) * (1.0f - ev);
            P2[mti][r] = (1.0f - bv) * ev;
        }
    }

    // ---- one-time: drive -> g, beta*drive -> drv ----
    float g[2][2][4], m_[2][2][4], drv[2][2][4];
    #pragma unroll
    for (int mti = 0; mti < 2; ++mti) {
        const int ch0 = (w * 2 + mti) * 16 + kg * 4;
        #pragma unroll
        for (int nt = 0; nt < 2; ++nt) {
            const size_t row = rowBase + (size_t)(nt * 16 + cl);
            const f32x4 d4 = *(const f32x4*)(drive + row * C_DIM + ch0);
            #pragma unroll
            for (int r = 0; r < 4; ++r) {
                const float bv = beta_[ch0 + r];
                g[mti][nt][r]   = d4[r];
                drv[mti][nt][r] = bv * d4[r];
            }
        }
    }

    // ---- precompute LDS addresses (swizzle: p = c ^ (m&7), bits 0-2) ----
    int rbase[2], woff[2][2];
    #pragma unroll
    for (int nt = 0; nt < 2; ++nt) {
        const int m = nt * 16 + cl;
        // read: c = kb*4 + kg -> p = (kb<<2) ^ kg ^ (m&7); kb folded via addr^(kb<<6)
        rbase[nt] = (m << 9) + ((kg ^ (m & 7)) << 4);
        #pragma unroll
        for (int mti = 0; mti < 2; ++mti) {
            const int c = (w * 2 + mti) * 2 + (kg >> 1);     // write chunk
            const int p = c ^ (m & 7);
            woff[mti][nt] = (m << 9) + (p << 4) + ((kg & 1) << 3);
        }
    }

    // ---- prologue: E for step 0 into buf0 ----
    #pragma unroll
    for (int mti = 0; mti < 2; ++mti) {
        #pragma unroll
        for (int nt = 0; nt < 2; ++nt) {
            f16x4 hv, lv;
            #pragma unroll
            for (int r = 0; r < 4; ++r) {
                const float gv = g[mti][nt][r];
                const float mv = rr[mti][r] * gv * (1.0f - gv);
                m_[mti][nt][r] = mv;
                const f16 hh = (f16)mv;
                hv[r] = hh;
                lv[r] = (f16)((mv - (float)hh) * 4096.0f);
            }
            *(f16x4*)(smem + woff[mti][nt]) = hv;
            *(f16x4*)(smem + woff[mti][nt] + 16384) = lv;
        }
    }

    #pragma unroll 1
    for (int s = 0; s < STEPS; ++s) {
        __syncthreads();                       // planes for step s complete
        const int rb = (s & 1) << 15;          // current buffer
        const int wb = rb ^ 32768;             // next buffer

        #pragma unroll
        for (int nt = 0; nt < 2; ++nt) {
            f32x4 acch[2], accl[2];
            #pragma unroll
            for (int mti = 0; mti < 2; ++mti) {
                acch[mti] = (f32x4)0.0f;
                accl[mti] = (f32x4)0.0f;
            }

            const int Ab = rbase[nt] | rb;
            #pragma unroll
            for (int kb = 0; kb < 8; ++kb) {
                const int addr = Ab ^ (kb << 6);
                const f16x8 bh = *(const f16x8*)(smem + addr);
                const f16x8 bl = *(const f16x8*)(smem + addr + 16384);
                #pragma unroll
                for (int mti = 0; mti < 2; ++mti) {
                    acch[mti] = __builtin_amdgcn_mfma_f32_16x16x32_f16(Wh[mti][kb], bh, acch[mti], 0, 0, 0);
                    accl[mti] = __builtin_amdgcn_mfma_f32_16x16x32_f16(Wl[mti][kb], bh, accl[mti], 0, 0, 0);
                    accl[mti] = __builtin_amdgcn_mfma_f32_16x16x32_f16(Wh[mti][kb], bl, accl[mti], 0, 0, 0);
                }
            }

            // physics + next-step map/split/write for this nt half
            #pragma unroll
            for (int mti = 0; mti < 2; ++mti) {
                f16x4 hv, lv;
                #pragma unroll
                for (int r = 0; r < 4; ++r) {
                    const float coupled = fmaf(accl[mti][r], 1.0f / 4096.0f, acch[mti][r]);
                    const float gn = fmaf(P1[mti][r], m_[mti][nt][r],
                                     fmaf(P2[mti][r], coupled, drv[mti][nt][r]));
                    g[mti][nt][r] = gn;
                    const float mv = rr[mti][r] * gn * (1.0f - gn);
                    m_[mti][nt][r] = mv;
                    const f16 hh = (f16)mv;
                    hv[r] = hh;
                    lv[r] = (f16)((mv - (float)hh) * 4096.0f);
                }
                if (s != STEPS - 1) {
                    *(f16x4*)(smem + (woff[mti][nt] | wb)) = hv;
                    *(f16x4*)(smem + (woff[mti][nt] | wb) + 16384) = lv;
                }
            }
        }
    }

    // ---- epilogue: clip + store ----
    #pragma unroll
    for (int mti = 0; mti < 2; ++mti) {
        const int ch0 = (w * 2 + mti) * 16 + kg * 4;
        #pragma unroll
        for (int nt = 0; nt < 2; ++nt) {
            const size_t row = rowBase + (size_t)(nt * 16 + cl);
            f32x4 o;
            #pragma unroll
            for (int r = 0; r < 4; ++r) {
                o[r] = fminf(fmaxf(g[mti][nt][r], 1e-4f), 1.0f - 1e-4f);
            }
            *(f32x4*)(out + row * C_DIM + ch0) = o;
        }
    }
}

extern "C" void kernel_launch(void* const* d_in, const int* in_sizes, int n_in,
                              void* d_out, int out_size, void* d_ws, size_t ws_size,
                              hipStream_t stream) {
    (void)n_in; (void)ws_size; (void)out_size;
    const float* drive = (const float*)d_in[0];
    const float* r     = (const float*)d_in[1];
    const float* eps   = (const float*)d_in[2];
    const float* beta  = (const float*)d_in[3];
    const float* Kl    = (const float*)d_in[4];
    const float* W     = (const float*)d_in[5];
    float* out = (float*)d_out;

    f16* whi = (f16*)d_ws;            // 128 KiB
    f16* wlo = whi + 65536;           // 128 KiB

    prep_w<<<dim3(32), dim3(256), 0, stream>>>(W, Kl, whi, wlo);

    const int nrows = in_sizes[0] / C_DIM;        // 131072
    cml_main<<<dim3((unsigned)(nrows / ROWS_PER_WG)), dim3(512), 0, stream>>>(
        drive, r, eps, beta, whi, wlo, out);
}